// Round 2
// baseline (2066.357 us; speedup 1.0000x reference)
//
#include <hip/hip_runtime.h>
#include <math.h>

#define B_    16
#define T_    4096
#define SEM   512
#define ACO   32
#define XROWS 544
#define CODES 2048
#define EPSC  1e-5f
#define HALFC 4.0f

// ---- workspace layout (floats) ----
// embT : [512][2048]  at ws + 0            (4 MiB)   embT[d][c] = esum[c][d]/clip(usage[c])
// bias : [2048]       at ws + 512*2048     (8 KiB)   bias[c] = 0.5*|e_c|^2
// codes: [16*4096] int after bias          (256 KiB)

// ============ kernel 1: per-code bias = 0.5*|e|^2 ============
__global__ void bias_kernel(const float* __restrict__ esum,
                            const float* __restrict__ usage,
                            float* __restrict__ bias) {
    int c = blockIdx.x;
    float u = fmaxf(usage[c], EPSC);
    float s = 0.f;
    for (int d = threadIdx.x; d < SEM; d += 64) {
        float v = esum[(size_t)c * SEM + d] / u;
        s += v * v;
    }
    for (int off = 32; off; off >>= 1) s += __shfl_down(s, off);
    if (threadIdx.x == 0) bias[c] = 0.5f * s;
}

// ============ kernel 2: embT[d][c] = esum[c][d] / clip(usage[c]) ============
__global__ void embT_kernel(const float* __restrict__ esum,
                            const float* __restrict__ usage,
                            float* __restrict__ embT) {
    __shared__ float tile[32][33];
    int c0 = blockIdx.x * 32;
    int d0 = blockIdx.y * 32;
    int col = threadIdx.x & 31, r = threadIdx.x >> 5;  // 256 threads: r=0..7
    for (int i = r; i < 32; i += 8) {
        float u = fmaxf(usage[c0 + i], EPSC);
        tile[col][i] = esum[(size_t)(c0 + i) * SEM + d0 + col] / u;
    }
    __syncthreads();
    for (int i = r; i < 32; i += 8)
        embT[(size_t)(d0 + i) * CODES + c0 + col] = tile[i][col];
}

// ============ kernel 3: fused GEMM + argmin ============
// score(m,c) = x_m . e_c - 0.5*|e_c|^2 ; argmax == argmin of d2.
// 512 threads (8 waves) per block, 128 queries x 128-code chunks,
// 4x8 micro-tile per thread, register-prefetch of next k-tile.
#define MT 128
#define NT 128
#define KT 32
__global__ __launch_bounds__(512, 4) void argmin_kernel(
        const float* __restrict__ x, const float* __restrict__ embT,
        const float* __restrict__ bias, int* __restrict__ codes_ws,
        float* __restrict__ codes_out) {
    __shared__ float Xs[KT][MT];
    __shared__ float Es[KT][NT];
    int tid = threadIdx.x;          // 0..511
    int tx = tid & 31;              // m-group: queries tx*4 .. tx*4+3
    int ty = tid >> 5;              // 0..15 : codes ty*8 .. ty*8+7
    int m0 = blockIdx.x * MT;
    int b  = m0 >> 12;              // /4096
    int t0 = m0 & 4095;
    const float* xbase = x + (size_t)b * XROWS * T_ + t0; // xbase[d*T_ + m]

    int lrow = tid >> 5;            // staging row 0..15 (and +16)
    int lcol = (tid & 31) * 4;      // staging col (floats)

    float best[4];
    int   bidx[4];
#pragma unroll
    for (int i = 0; i < 4; i++) { best[i] = -3.4e38f; bidx[i] = 0; }

    for (int n0 = 0; n0 < CODES; n0 += NT) {
        float acc[4][8];
#pragma unroll
        for (int i = 0; i < 4; i++)
#pragma unroll
            for (int j = 0; j < 8; j++) acc[i][j] = 0.f;

        // prologue: prefetch k-tile 0 into registers
        float4 nX0 = *(const float4*)(xbase + (size_t)lrow * T_ + lcol);
        float4 nX1 = *(const float4*)(xbase + (size_t)(lrow + 16) * T_ + lcol);
        float4 nE0 = *(const float4*)(embT + (size_t)lrow * CODES + n0 + lcol);
        float4 nE1 = *(const float4*)(embT + (size_t)(lrow + 16) * CODES + n0 + lcol);

        for (int k0 = 0; k0 < SEM; k0 += KT) {
            __syncthreads();   // previous tile fully consumed
            *(float4*)&Xs[lrow][lcol]      = nX0;
            *(float4*)&Xs[lrow + 16][lcol] = nX1;
            *(float4*)&Es[lrow][lcol]      = nE0;
            *(float4*)&Es[lrow + 16][lcol] = nE1;
            __syncthreads();
            if (k0 + KT < SEM) {   // prefetch next k-tile (hidden behind FMAs)
                int kn = k0 + KT;
                nX0 = *(const float4*)(xbase + (size_t)(kn + lrow) * T_ + lcol);
                nX1 = *(const float4*)(xbase + (size_t)(kn + lrow + 16) * T_ + lcol);
                nE0 = *(const float4*)(embT + (size_t)(kn + lrow) * CODES + n0 + lcol);
                nE1 = *(const float4*)(embT + (size_t)(kn + lrow + 16) * CODES + n0 + lcol);
            }
#pragma unroll
            for (int kk = 0; kk < KT; kk++) {
                float xa[4], ea[8];
                *(float4*)&xa[0] = *(const float4*)&Xs[kk][tx * 4];
                *(float4*)&ea[0] = *(const float4*)&Es[kk][ty * 8];
                *(float4*)&ea[4] = *(const float4*)&Es[kk][ty * 8 + 4];
#pragma unroll
                for (int i = 0; i < 4; i++)
#pragma unroll
                    for (int j = 0; j < 8; j++)
                        acc[i][j] = fmaf(xa[i], ea[j], acc[i][j]);
            }
        }
        // fold bias, update running argmax (per-thread n ascending -> '>' keeps smallest idx)
#pragma unroll
        for (int j = 0; j < 8; j++) {
            int n = n0 + ty * 8 + j;
            float bsub = bias[n];
#pragma unroll
            for (int i = 0; i < 4; i++) {
                float s = acc[i][j] - bsub;
                if (s > best[i]) { best[i] = s; bidx[i] = n; }
            }
        }
    }

    // cross-thread (ty) reduction per query
    __syncthreads();
    float* sbest = &Xs[0][0];           // 16*128 floats (Xs has 32*128)
    int*   sidx  = (int*)&Es[0][0];
#pragma unroll
    for (int i = 0; i < 4; i++) {
        int m = tx * 4 + i;
        sbest[ty * MT + m] = best[i];
        sidx [ty * MT + m] = bidx[i];
    }
    __syncthreads();
    if (tid < MT) {
        int m = tid;
        float bb = sbest[m]; int bi = sidx[m];
        for (int r = 1; r < 16; r++) {
            float v = sbest[r * MT + m]; int vi = sidx[r * MT + m];
            if (v > bb || (v == bb && vi < bi)) { bb = v; bi = vi; }
        }
        codes_ws[m0 + m] = bi;
        // codes output row 0 of [b][33][t]
        codes_out[(size_t)b * 33 * T_ + (t0 + m)] = (float)bi;
    }
}

// ============ kernel 4: finalize (sem select/gather + aco path) ============
__global__ void finalize_kernel(const float* __restrict__ x,
                                const float* __restrict__ embT,
                                const int* __restrict__ codes_ws,
                                const float* __restrict__ noise,
                                const float* __restrict__ probs_sem,
                                const float* __restrict__ probs_aco,
                                float* __restrict__ out,
                                float* __restrict__ codes_out) {
    const size_t N0 = (size_t)B_ * SEM * T_;   // 33,554,432
    const size_t N1 = (size_t)B_ * ACO * T_;   // 2,097,152
    size_t idx = (size_t)blockIdx.x * 256 + threadIdx.x;
    if (idx < N0) {
        int t = (int)(idx & 4095);
        int d = (int)((idx >> 12) & 511);
        int b = (int)(idx >> 21);
        float v;
        if (probs_sem[b] < 0.5f) {
            int c = codes_ws[(b << 12) + t];
            v = embT[(size_t)d * CODES + c];
        } else {
            v = x[((size_t)(b * XROWS + d)) * T_ + t];
        }
        out[((size_t)(b * XROWS + d)) * T_ + t] = v;
    } else if (idx < N0 + N1) {
        size_t i2 = idx - N0;
        int t = (int)(i2 & 4095);
        int j = (int)((i2 >> 12) & 31);
        int b = (int)(i2 >> 17);
        float a  = x[((size_t)(b * XROWS + SEM + j)) * T_ + t];
        float zb = tanhf(a) * HALFC;
        float p  = probs_aco[b];
        float zo;
        if (p < 0.5f) {
            zo = rintf(zb);                         // round-half-even, matches jnp.round
        } else if (p < 0.75f) {
            float nz = noise[((size_t)(b * ACO + j)) * T_ + t];
            float ns = ((nz * 2.0f - 1.0f) * (float)(1.0 / 9.0)) * HALFC;
            zo = fminf(fmaxf(zb + ns, -HALFC), HALFC);
        } else {
            zo = zb;
        }
        float code = fminf(fmaxf(rintf(zo + HALFC), 0.f), 8.f);
        out[((size_t)(b * XROWS + SEM + j)) * T_ + t] = zo * 0.25f;
        codes_out[((size_t)(b * 33 + 1 + j)) * T_ + t] = code;
    }
}

extern "C" void kernel_launch(void* const* d_in, const int* in_sizes, int n_in,
                              void* d_out, int out_size, void* d_ws, size_t ws_size,
                              hipStream_t stream) {
    const float* x      = (const float*)d_in[0];
    const float* esum   = (const float*)d_in[1];
    const float* usage  = (const float*)d_in[2];
    const float* noise  = (const float*)d_in[3];
    const float* psem   = (const float*)d_in[4];
    const float* paco   = (const float*)d_in[5];
    float* out = (float*)d_out;

    float* embT   = (float*)d_ws;
    float* bias   = embT + (size_t)SEM * CODES;
    int*   codesW = (int*)(bias + CODES);

    const size_t QOFF = (size_t)B_ * XROWS * T_;   // 35,651,584
    float* codes_out = out + QOFF;

    bias_kernel<<<CODES, 64, 0, stream>>>(esum, usage, bias);
    embT_kernel<<<dim3(CODES / 32, SEM / 32), 256, 0, stream>>>(esum, usage, embT);
    argmin_kernel<<<(B_ * T_) / MT, 512, 0, stream>>>(x, embT, bias, codesW, codes_out);
    const size_t NTOT = (size_t)B_ * SEM * T_ + (size_t)B_ * ACO * T_;
    finalize_kernel<<<(int)(NTOT / 256), 256, 0, stream>>>(x, embT, codesW, noise,
                                                           psem, paco, out, codes_out);
}

// Round 3
// 883.152 us; speedup vs baseline: 2.3398x; 2.3398x over previous
//
#include <hip/hip_runtime.h>
#include <math.h>

typedef _Float16 f16;
typedef _Float16 f16x8 __attribute__((ext_vector_type(8)));
typedef float f32x4 __attribute__((ext_vector_type(4)));

#define B_    16
#define T_    4096
#define SEM   512
#define ACO   32
#define XROWS 544
#define CODES 2048
#define EPSC  1e-5f
#define HALFC 4.0f
#define ECLAMP 60000.0f

// ---- ws layout (float units) ----
// embT   [0, 1048576)              fp32 [512][2048] for finalize gather
// bias   [1048576, 1050624)        0.5*|e|^2
// codesW [1050624, 1116160)        int[65536]
// EhT    [1116160, 1640448)        f16[2048][512] (high half)
// ElT    [1640448, 2164736)        f16[2048][512] (low half)
// pScore [2164736, 2426880)        float[4][65536]
// pIdx   [2426880, 2689024)        int[4][65536]

// ============ kernel 1: per-code bias = 0.5*|e|^2 ============
__global__ void bias_kernel(const float* __restrict__ esum,
                            const float* __restrict__ usage,
                            float* __restrict__ bias) {
    int c = blockIdx.x;
    float u = fmaxf(usage[c], EPSC);
    float s = 0.f;
    for (int d = threadIdx.x; d < SEM; d += 64) {
        float v = esum[(size_t)c * SEM + d] / u;
        s += v * v;
    }
    for (int off = 32; off; off >>= 1) s += __shfl_down(s, off);
    if (threadIdx.x == 0) bias[c] = 0.5f * s;
}

// ============ kernel 2: embT[d][c] = esum[c][d] / clip(usage[c]) ============
__global__ void embT_kernel(const float* __restrict__ esum,
                            const float* __restrict__ usage,
                            float* __restrict__ embT) {
    __shared__ float tile[32][33];
    int c0 = blockIdx.x * 32;
    int d0 = blockIdx.y * 32;
    int col = threadIdx.x & 31, r = threadIdx.x >> 5;  // 256 threads: r=0..7
    for (int i = r; i < 32; i += 8) {
        float u = fmaxf(usage[c0 + i], EPSC);
        tile[col][i] = esum[(size_t)(c0 + i) * SEM + d0 + col] / u;
    }
    __syncthreads();
    for (int i = r; i < 32; i += 8)
        embT[(size_t)(d0 + i) * CODES + c0 + col] = tile[i][col];
}

// ============ kernel 3: f16 hi/lo split planes of emb, [c][d] layout ============
__global__ void esplit_kernel(const float* __restrict__ esum,
                              const float* __restrict__ usage,
                              f16* __restrict__ EhT, f16* __restrict__ ElT) {
    int c = blockIdx.x;
    float u = fmaxf(usage[c], EPSC);
    for (int d = threadIdx.x; d < SEM; d += 256) {
        float e = esum[(size_t)c * SEM + d] / u;
        e = fminf(fmaxf(e, -ECLAMP), ECLAMP);
        f16 h = (f16)e;
        EhT[(size_t)c * SEM + d] = h;
        ElT[(size_t)c * SEM + d] = (f16)(e - (float)h);
    }
}

// ============ kernel 4: MFMA GEMM + fused argmin ============
#define MB 256
#define NQ 512
#define NC 128
#define BK 32
#define XPAD 258
__global__ __launch_bounds__(256, 2) void argmin_mfma(
        const float* __restrict__ x, const f16* __restrict__ EhT,
        const f16* __restrict__ ElT, const float* __restrict__ bias,
        float* __restrict__ pScore, int* __restrict__ pIdx) {
    __shared__ float Xs[BK * XPAD];        // [32][258] fp32, padded
    __shared__ f16 Eh[NC * 32];            // [128][32]
    __shared__ f16 El[NC * 32];

    int tid = threadIdx.x;
    int w   = tid >> 6;        // wave 0..3
    int l   = tid & 63;
    int q   = l >> 4;          // quad
    int r16 = l & 15;

    int m0      = blockIdx.x * MB;     // query base
    int quarter = blockIdx.y;          // 0..3 code quarter
    int b  = m0 >> 12;
    int t0 = m0 & 4095;
    const float* xb = x + (size_t)b * XROWS * T_ + t0;   // xb[k*T_ + m]

    float bestS[16];
    int   bestI[16];
#pragma unroll
    for (int i = 0; i < 16; i++) { bestS[i] = -3.4e38f; bestI[i] = 0; }

    for (int nc = 0; nc < 4; nc++) {
        int nbase = quarter * NQ + nc * NC;
        float bb[8];
#pragma unroll
        for (int ni = 0; ni < 8; ni++) bb[ni] = bias[nbase + ni * 16 + r16];

        f32x4 acc[4][8];
#pragma unroll
        for (int mi = 0; mi < 4; mi++)
#pragma unroll
            for (int ni = 0; ni < 8; ni++)
                acc[mi][ni] = (f32x4){0.f, 0.f, 0.f, 0.f};

        for (int k0 = 0; k0 < SEM; k0 += BK) {
            __syncthreads();   // previous tile fully consumed
            // stage X (fp32, native [k][m], padded rows): 32 rows x 256 cols
#pragma unroll
            for (int rr = 0; rr < 8; rr++) {
                int row = rr * 4 + w;
                float4 v = *(const float4*)(xb + (size_t)(k0 + row) * T_ + l * 4);
                *(float4*)&Xs[row * XPAD + l * 4] = v;
            }
            // stage E hi/lo tiles [128][32] f16
#pragma unroll
            for (int pp = 0; pp < 2; pp++) {
                int row = (tid >> 2) + pp * 64;
                int kc  = (tid & 3) * 8;
                size_t g = (size_t)(nbase + row) * SEM + k0 + kc;
                *(float4*)&Eh[row * 32 + kc] = *(const float4*)(EhT + g);
                *(float4*)&El[row * 32 + kc] = *(const float4*)(ElT + g);
            }
            __syncthreads();

            // a-frags: split fp32 -> f16 hi/lo in registers
            f16x8 ah[4], al[4];
#pragma unroll
            for (int mi = 0; mi < 4; mi++) {
                int m = w * 64 + mi * 16 + r16;
#pragma unroll
                for (int j = 0; j < 8; j++) {
                    float v = Xs[(q * 8 + j) * XPAD + m];
                    f16 h = (f16)v;
                    ah[mi][j] = h;
                    al[mi][j] = (f16)(v - (float)h);
                }
            }
#pragma unroll
            for (int ni = 0; ni < 8; ni++) {
                f16x8 bh = *(const f16x8*)&Eh[(ni * 16 + r16) * 32 + q * 8];
                f16x8 bl = *(const f16x8*)&El[(ni * 16 + r16) * 32 + q * 8];
#pragma unroll
                for (int mi = 0; mi < 4; mi++) {
                    f32x4 a0 = acc[mi][ni];
                    a0 = __builtin_amdgcn_mfma_f32_16x16x32_f16(al[mi], bh, a0, 0, 0, 0);
                    a0 = __builtin_amdgcn_mfma_f32_16x16x32_f16(ah[mi], bl, a0, 0, 0, 0);
                    a0 = __builtin_amdgcn_mfma_f32_16x16x32_f16(ah[mi], bh, a0, 0, 0, 0);
                    acc[mi][ni] = a0;
                }
            }
        }
        // epilogue: fold bias, update per-lane argmax (n ascending -> smallest idx kept)
#pragma unroll
        for (int ni = 0; ni < 8; ni++) {
            int n = nbase + ni * 16 + r16;
#pragma unroll
            for (int mi = 0; mi < 4; mi++)
#pragma unroll
                for (int reg = 0; reg < 4; reg++) {
                    float s = acc[mi][ni][reg] - bb[ni];
                    int slot = mi * 4 + reg;
                    if (s > bestS[slot]) { bestS[slot] = s; bestI[slot] = n; }
                }
        }
    }

    // reduce across the 16 column-lanes (bits 0..3), tie -> smallest idx
#pragma unroll
    for (int mask = 1; mask < 16; mask <<= 1) {
#pragma unroll
        for (int slot = 0; slot < 16; slot++) {
            float os = __shfl_xor(bestS[slot], mask);
            int   oi = __shfl_xor(bestI[slot], mask);
            if (os > bestS[slot] || (os == bestS[slot] && oi < bestI[slot])) {
                bestS[slot] = os; bestI[slot] = oi;
            }
        }
    }
    if (r16 == 0) {
#pragma unroll
        for (int mi = 0; mi < 4; mi++)
#pragma unroll
            for (int reg = 0; reg < 4; reg++) {
                int m = m0 + w * 64 + mi * 16 + q * 4 + reg;
                pScore[quarter * 65536 + m] = bestS[mi * 4 + reg];
                pIdx  [quarter * 65536 + m] = bestI[mi * 4 + reg];
            }
    }
}

// ============ kernel 5: merge the 4 quarter-partials ============
__global__ void merge_kernel(const float* __restrict__ pScore,
                             const int* __restrict__ pIdx,
                             int* __restrict__ codesW,
                             float* __restrict__ codes_out) {
    int m = blockIdx.x * 256 + threadIdx.x;
    float bs = pScore[m]; int bi = pIdx[m];
    for (int qq = 1; qq < 4; qq++) {
        float s = pScore[qq * 65536 + m];
        int  ii = pIdx[qq * 65536 + m];
        if (s > bs || (s == bs && ii < bi)) { bs = s; bi = ii; }
    }
    codesW[m] = bi;
    int bb2 = m >> 12, t = m & 4095;
    codes_out[(size_t)bb2 * 33 * T_ + t] = (float)bi;
}

// ============ kernel 6: finalize (sem select/gather + aco path) ============
__global__ void finalize_kernel(const float* __restrict__ x,
                                const float* __restrict__ embT,
                                const int* __restrict__ codes_ws,
                                const float* __restrict__ noise,
                                const float* __restrict__ probs_sem,
                                const float* __restrict__ probs_aco,
                                float* __restrict__ out,
                                float* __restrict__ codes_out) {
    const size_t N0 = (size_t)B_ * SEM * T_;   // 33,554,432
    const size_t N1 = (size_t)B_ * ACO * T_;   // 2,097,152
    size_t idx = (size_t)blockIdx.x * 256 + threadIdx.x;
    if (idx < N0) {
        int t = (int)(idx & 4095);
        int d = (int)((idx >> 12) & 511);
        int b = (int)(idx >> 21);
        float v;
        if (probs_sem[b] < 0.5f) {
            int c = codes_ws[(b << 12) + t];
            v = embT[(size_t)d * CODES + c];
        } else {
            v = x[((size_t)(b * XROWS + d)) * T_ + t];
        }
        out[((size_t)(b * XROWS + d)) * T_ + t] = v;
    } else if (idx < N0 + N1) {
        size_t i2 = idx - N0;
        int t = (int)(i2 & 4095);
        int j = (int)((i2 >> 12) & 31);
        int b = (int)(i2 >> 17);
        float a  = x[((size_t)(b * XROWS + SEM + j)) * T_ + t];
        float zb = tanhf(a) * HALFC;
        float p  = probs_aco[b];
        float zo;
        if (p < 0.5f) {
            zo = rintf(zb);                         // round-half-even, matches jnp.round
        } else if (p < 0.75f) {
            float nz = noise[((size_t)(b * ACO + j)) * T_ + t];
            float ns = ((nz * 2.0f - 1.0f) * (float)(1.0 / 9.0)) * HALFC;
            zo = fminf(fmaxf(zb + ns, -HALFC), HALFC);
        } else {
            zo = zb;
        }
        float code = fminf(fmaxf(rintf(zo + HALFC), 0.f), 8.f);
        out[((size_t)(b * XROWS + SEM + j)) * T_ + t] = zo * 0.25f;
        codes_out[((size_t)(b * 33 + 1 + j)) * T_ + t] = code;
    }
}

extern "C" void kernel_launch(void* const* d_in, const int* in_sizes, int n_in,
                              void* d_out, int out_size, void* d_ws, size_t ws_size,
                              hipStream_t stream) {
    const float* x      = (const float*)d_in[0];
    const float* esum   = (const float*)d_in[1];
    const float* usage  = (const float*)d_in[2];
    const float* noise  = (const float*)d_in[3];
    const float* psem   = (const float*)d_in[4];
    const float* paco   = (const float*)d_in[5];
    float* out = (float*)d_out;

    float* wsf    = (float*)d_ws;
    float* embT   = wsf;
    float* bias   = wsf + 1048576;
    int*   codesW = (int*)(wsf + 1050624);
    f16*   EhT    = (f16*)(wsf + 1116160);
    f16*   ElT    = (f16*)(wsf + 1640448);
    float* pScore = wsf + 2164736;
    int*   pIdx   = (int*)(wsf + 2426880);

    const size_t QOFF = (size_t)B_ * XROWS * T_;   // 35,651,584
    float* codes_out = out + QOFF;

    bias_kernel<<<CODES, 64, 0, stream>>>(esum, usage, bias);
    embT_kernel<<<dim3(CODES / 32, SEM / 32), 256, 0, stream>>>(esum, usage, embT);
    esplit_kernel<<<CODES, 256, 0, stream>>>(esum, usage, EhT, ElT);
    argmin_mfma<<<dim3((B_ * T_) / MB, 4), 256, 0, stream>>>(x, EhT, ElT, bias,
                                                             pScore, pIdx);
    merge_kernel<<<(B_ * T_) / 256, 256, 0, stream>>>(pScore, pIdx, codesW, codes_out);
    const size_t NTOT = (size_t)B_ * SEM * T_ + (size_t)B_ * ACO * T_;
    finalize_kernel<<<(int)(NTOT / 256), 256, 0, stream>>>(x, embT, codesW, noise,
                                                           psem, paco, out, codes_out);
}